// Round 1
// baseline (601.551 us; speedup 1.0000x reference)
//
#include <hip/hip_runtime.h>
#include <stdint.h>

typedef __attribute__((ext_vector_type(8))) short short8;
typedef __attribute__((ext_vector_type(4))) float floatx4;
typedef __attribute__((ext_vector_type(4))) unsigned short u16x4;

#define Hh 384
#define Ww 384
#define Cc 11
#define Nn 32
#define PITCH 72  // 64 + 8 pad bf16 elems; 144 B rows: 16B-aligned, conflict-free b128

__device__ __forceinline__ unsigned short f2bf(float f) {
  union { float f; uint32_t u; } z; z.f = f;
  return (unsigned short)(z.u >> 16);   // truncation: 1 op; bias negligible vs 2% threshold
}
__device__ __forceinline__ float bf2f(unsigned short b) {
  union { uint32_t u; float f; } z; z.u = ((uint32_t)b) << 16;
  return z.f;
}

__global__ __launch_bounds__(256, 3)
void center_loss(const float* __restrict__ X, const float* __restrict__ Cen,
                 const int* __restrict__ Lab, float* __restrict__ Out) {
  __shared__ __align__(16) unsigned short Alds[64 * PITCH];  // A[i][k]  (x rows)
  __shared__ __align__(16) unsigned short Blds[64 * PITCH];  // Bt[j][k] (centers cols)
  __shared__ float red[4];

  const int bx = blockIdx.x;
  const int n  = bx / 36;
  const int t36 = bx - n * 36;
  const int ib = t36 / 6;
  const int jb = t36 - ib * 6;
  const int i0 = ib << 6, j0 = jb << 6;

  const int t   = threadIdx.x;
  const int l   = t & 63;
  const int w   = t >> 6;
  const int wr  = (w >> 1) << 5;   // wave row base in tile
  const int wc  = (w & 1) << 5;    // wave col base in tile
  const int q4  = l >> 4;
  const int l16 = l & 15;
  const int sa  = t & 15;          // A staging: col segment
  const int sr  = t >> 4;          // A staging: row base

  float m[16], s[16];
#pragma unroll
  for (int i = 0; i < 16; ++i) { m[i] = -3.0e38f; s[i] = 0.0f; }

  for (int c = 0; c < Cc; ++c) {
    const float* xb = X   + (size_t)(n * Cc + c) * (Hh * Ww);
    const float* cb = Cen + (size_t)(n * Cc + c) * (Hh * Ww);

    floatx4 acc[2][2];
#pragma unroll
    for (int a = 0; a < 2; ++a)
#pragma unroll
      for (int b = 0; b < 2; ++b) acc[a][b] = (floatx4){0.f, 0.f, 0.f, 0.f};
    float ev[16];
#pragma unroll
    for (int i = 0; i < 16; ++i) ev[i] = 0.0f;

    for (int kb = 0; kb < 6; ++kb) {
      __syncthreads();
      // ---- stage A: x[i0..i0+63][kb*64..+63], row-parallel float4, cvt, b64 writes ----
      {
        const float* ap = xb + (size_t)(i0 + sr) * Ww + (kb << 6) + (sa << 2);
#pragma unroll
        for (int p = 0; p < 4; ++p) {
          float4 v = *reinterpret_cast<const float4*>(ap + (size_t)(p * 16) * Ww);
          u16x4 pk;
          pk.x = f2bf(v.x); pk.y = f2bf(v.y); pk.z = f2bf(v.z); pk.w = f2bf(v.w);
          *reinterpret_cast<u16x4*>(&Alds[(sr + 16 * p) * PITCH + (sa << 2)]) = pk;
        }
      }
      // ---- stage B transposed: lane = column j; 8 coalesced dword column loads,
      //      pack 8 bf16, one conflict-free ds_write_b128 into Bt[j][k] ----
      {
#pragma unroll
        for (int p = 0; p < 2; ++p) {
          const int kbase = (w << 3) + (p << 5);
          const float* bp = cb + (size_t)((kb << 6) + kbase) * Ww + j0 + l;
          short8 pk;
#pragma unroll
          for (int u = 0; u < 8; ++u) pk[u] = (short)f2bf(bp[(size_t)u * Ww]);
          *reinterpret_cast<short8*>(&Blds[l * PITCH + kbase]) = pk;
        }
      }
      __syncthreads();

      // ---- epilogue-term capture from LDS (free re-use of staged tiles) ----
      if (kb == jb) {   // A tile currently holds x[i0..][j0..j0+63]
#pragma unroll
        for (int fr = 0; fr < 2; ++fr)
#pragma unroll
          for (int fc = 0; fc < 2; ++fc)
#pragma unroll
            for (int r = 0; r < 4; ++r) {
              const int idx = ((fr << 1) + fc) * 4 + r;
              const int pr = wr + (fr << 4) + (q4 << 2) + r;
              const int pc = wc + (fc << 4) + l16;
              float xv = bf2f(Alds[pr * PITCH + pc]);
              ev[idx] += xv * xv;
            }
      }
      if (kb == ib) {   // Bt tile currently holds centers[i0..i0+63][j0..]^T
#pragma unroll
        for (int fr = 0; fr < 2; ++fr)
#pragma unroll
          for (int fc = 0; fc < 2; ++fc)
#pragma unroll
            for (int r = 0; r < 4; ++r) {
              const int idx = ((fr << 1) + fc) * 4 + r;
              const int pr = wr + (fr << 4) + (q4 << 2) + r;
              const int pc = wc + (fc << 4) + l16;
              float cv = bf2f(Blds[pc * PITCH + pr]);
              ev[idx] += cv * cv;
            }
      }

      // ---- MFMA inner loop: 2 k-steps of 32 ----
#pragma unroll
      for (int ks = 0; ks < 2; ++ks) {
        const int ko = (ks << 5) + (q4 << 3);
        short8 a0 = *reinterpret_cast<const short8*>(&Alds[(wr +      l16) * PITCH + ko]);
        short8 a1 = *reinterpret_cast<const short8*>(&Alds[(wr + 16 + l16) * PITCH + ko]);
        short8 b0 = *reinterpret_cast<const short8*>(&Blds[(wc +      l16) * PITCH + ko]);
        short8 b1 = *reinterpret_cast<const short8*>(&Blds[(wc + 16 + l16) * PITCH + ko]);
        acc[0][0] = __builtin_amdgcn_mfma_f32_16x16x32_bf16(a0, b0, acc[0][0], 0, 0, 0);
        acc[0][1] = __builtin_amdgcn_mfma_f32_16x16x32_bf16(a0, b1, acc[0][1], 0, 0, 0);
        acc[1][0] = __builtin_amdgcn_mfma_f32_16x16x32_bf16(a1, b0, acc[1][0], 0, 0, 0);
        acc[1][1] = __builtin_amdgcn_mfma_f32_16x16x32_bf16(a1, b1, acc[1][1], 0, 0, 0);
      }
    } // kb

    // ---- online softmax update for this channel ----
#pragma unroll
    for (int fr = 0; fr < 2; ++fr)
#pragma unroll
      for (int fc = 0; fc < 2; ++fc)
#pragma unroll
        for (int r = 0; r < 4; ++r) {
          const int idx = ((fr << 1) + fc) * 4 + r;
          float res = ev[idx] - 2.0f * acc[fr][fc][r];
          float mi = m[idx];
          if (res <= mi) {
            s[idx] += __expf(res - mi);
          } else {
            s[idx] = s[idx] * __expf(mi - res) + 1.0f;
            m[idx] = res;
          }
        }
  } // c

  // ---- max(softmax) = 1/s ; weight by label; clip; reduce ----
  float local = 0.0f;
  const int* lb = Lab + (size_t)n * (Hh * Ww);
#pragma unroll
  for (int fr = 0; fr < 2; ++fr)
#pragma unroll
    for (int fc = 0; fc < 2; ++fc)
#pragma unroll
      for (int r = 0; r < 4; ++r) {
        const int idx = ((fr << 1) + fc) * 4 + r;
        const int pr = i0 + wr + (fr << 4) + (q4 << 2) + r;
        const int pc = j0 + wc + (fc << 4) + l16;
        float val = 1.0f / s[idx];
        float d = val * (float)lb[pr * Ww + pc];
        d = fminf(fmaxf(d, 1e-12f), 1e12f);
        local += d;
      }
#pragma unroll
  for (int off = 32; off > 0; off >>= 1) local += __shfl_down(local, off, 64);
  if (l == 0) red[w] = local;
  __syncthreads();
  if (t == 0) {
    float bs = (red[0] + red[1] + red[2] + red[3]) * (1.0f / 4718592.0f);
    atomicAdd(Out, bs);
  }
}

extern "C" void kernel_launch(void* const* d_in, const int* in_sizes, int n_in,
                              void* d_out, int out_size, void* d_ws, size_t ws_size,
                              hipStream_t stream) {
  const float* X   = (const float*)d_in[0];
  const float* Cen = (const float*)d_in[1];
  const int*   Lab = (const int*)d_in[2];
  float* Out = (float*)d_out;
  hipMemsetAsync(Out, 0, (size_t)out_size * sizeof(float), stream);
  hipLaunchKernelGGL(center_loss, dim3(Nn * 36), dim3(256), 0, stream,
                     X, Cen, Lab, Out);
}

// Round 3
// 494.689 us; speedup vs baseline: 1.2160x; 1.2160x over previous
//
#include <hip/hip_runtime.h>
#include <stdint.h>

typedef __attribute__((ext_vector_type(8))) short short8;
typedef __attribute__((ext_vector_type(4))) float floatx4;
typedef __attribute__((ext_vector_type(4))) unsigned short u16x4;

#define Hh 384
#define Ww 384
#define Cc 11
#define Nn 32
#define PITCH 72  // 64 + 8 pad bf16 elems; 144 B rows: 16B-aligned, conflict-free b128

__device__ __forceinline__ unsigned short f2bf(float f) {
  union { float f; uint32_t u; } z; z.f = f;
  return (unsigned short)(z.u >> 16);
}
__device__ __forceinline__ float bf2f(unsigned short b) {
  union { uint32_t u; float f; } z; z.u = ((uint32_t)b) << 16;
  return z.f;
}

__global__ __launch_bounds__(256, 4)
void center_loss(const float* __restrict__ X, const float* __restrict__ Cen,
                 const int* __restrict__ Lab, float* __restrict__ Out) {
  __shared__ __align__(16) unsigned short Alds[64 * PITCH];  // A[i][k]  (x rows)
  __shared__ __align__(16) unsigned short Blds[64 * PITCH];  // Bt[j][k] (centers cols)
  __shared__ float red[4];

  // XCD swizzle: dispatcher round-robins block i -> XCD i%8. Map so all 36
  // blocks of one n share an XCD: per-channel working set (1.18 MB) fits 4MB L2.
  const int bx   = blockIdx.x;
  const int xcd  = bx & 7;
  const int slot = bx >> 3;          // 0..143
  const int grp  = slot / 36;        // 0..3
  const int t36  = slot - grp * 36;
  const int n    = xcd + (grp << 3); // 0..31
  const int ib = t36 / 6;
  const int jb = t36 - ib * 6;
  const int i0 = ib << 6, j0 = jb << 6;

  const int t   = threadIdx.x;
  const int l   = t & 63;
  const int w   = t >> 6;
  const int wr  = (w >> 1) << 5;
  const int wc  = (w & 1) << 5;
  const int q4  = l >> 4;
  const int l16 = l & 15;
  const int sa  = t & 15;            // A staging: col segment
  const int sr  = t >> 4;            // A staging: row base

  const size_t plane = (size_t)Hh * Ww;
  const float* xbase = X   + (size_t)n * Cc * plane;
  const float* cbase = Cen + (size_t)n * Cc * plane;

  float m[16], s[16];
#pragma unroll
  for (int i = 0; i < 16; ++i) { m[i] = -3.0e38f; s[i] = 0.0f; }

  floatx4 acc[2][2];
  float ev[16];
#pragma unroll
  for (int a = 0; a < 2; ++a)
#pragma unroll
    for (int b = 0; b < 2; ++b) acc[a][b] = (floatx4){0.f, 0.f, 0.f, 0.f};
#pragma unroll
  for (int i = 0; i < 16; ++i) ev[i] = 0.0f;

  // ---- prefetch registers (tile for the CURRENT iteration) ----
  float4 pa[4];
  float  pb[16];

  // initial load: (c=0, kb=0)
  {
    const float* ap = xbase + (size_t)(i0 + sr) * Ww + (sa << 2);
#pragma unroll
    for (int p = 0; p < 4; ++p)
      pa[p] = *reinterpret_cast<const float4*>(ap + (size_t)(p * 16) * Ww);
#pragma unroll
    for (int p = 0; p < 2; ++p) {
      const int kbase = (w << 3) + (p << 5);
      const float* bp = cbase + (size_t)kbase * Ww + j0 + l;
#pragma unroll
      for (int u = 0; u < 8; ++u) pb[p * 8 + u] = bp[(size_t)u * Ww];
    }
  }

  int c = 0, kb = 0;
  for (int it = 0; it < 66; ++it) {
    __syncthreads();   // previous iteration's LDS reads complete

    // ---- stage current tile from regs into LDS ----
#pragma unroll
    for (int p = 0; p < 4; ++p) {
      u16x4 pk;
      pk.x = f2bf(pa[p].x); pk.y = f2bf(pa[p].y);
      pk.z = f2bf(pa[p].z); pk.w = f2bf(pa[p].w);
      *reinterpret_cast<u16x4*>(&Alds[(sr + 16 * p) * PITCH + (sa << 2)]) = pk;
    }
#pragma unroll
    for (int p = 0; p < 2; ++p) {
      const int kbase = (w << 3) + (p << 5);
      short8 pk;
#pragma unroll
      for (int u = 0; u < 8; ++u) pk[u] = (short)f2bf(pb[p * 8 + u]);
      *reinterpret_cast<short8*>(&Blds[l * PITCH + kbase]) = pk;
    }

    // ---- issue next tile's global loads (in flight under sync+MFMA) ----
    int kn = kb + 1, cn = c;
    if (kn == 6) { kn = 0; cn = c + 1; }
    float4 na[4];
    float  nb[16];
    if (it < 65) {
      const float* xb = xbase + (size_t)cn * plane;
      const float* cb = cbase + (size_t)cn * plane;
      const float* ap = xb + (size_t)(i0 + sr) * Ww + (kn << 6) + (sa << 2);
#pragma unroll
      for (int p = 0; p < 4; ++p)
        na[p] = *reinterpret_cast<const float4*>(ap + (size_t)(p * 16) * Ww);
#pragma unroll
      for (int p = 0; p < 2; ++p) {
        const int kbase = (w << 3) + (p << 5);
        const float* bp = cb + (size_t)((kn << 6) + kbase) * Ww + j0 + l;
#pragma unroll
        for (int u = 0; u < 8; ++u) nb[p * 8 + u] = bp[(size_t)u * Ww];
      }
    }

    __syncthreads();   // LDS writes visible

    // ---- epilogue-term capture from LDS (free reuse of staged tiles) ----
    if (kb == jb) {    // A tile currently holds x[i0..][j0..j0+63]
#pragma unroll
      for (int fr = 0; fr < 2; ++fr)
#pragma unroll
        for (int fc = 0; fc < 2; ++fc)
#pragma unroll
          for (int r = 0; r < 4; ++r) {
            const int idx = ((fr << 1) + fc) * 4 + r;
            const int pr = wr + (fr << 4) + (q4 << 2) + r;
            const int pc = wc + (fc << 4) + l16;
            float xv = bf2f(Alds[pr * PITCH + pc]);
            ev[idx] += xv * xv;
          }
    }
    if (kb == ib) {    // Bt tile currently holds centers[..][..]^T
#pragma unroll
      for (int fr = 0; fr < 2; ++fr)
#pragma unroll
        for (int fc = 0; fc < 2; ++fc)
#pragma unroll
          for (int r = 0; r < 4; ++r) {
            const int idx = ((fr << 1) + fc) * 4 + r;
            const int pr = wr + (fr << 4) + (q4 << 2) + r;
            const int pc = wc + (fc << 4) + l16;
            float cv = bf2f(Blds[pc * PITCH + pr]);
            ev[idx] += cv * cv;
          }
    }

    // ---- MFMA: 2 k-steps of 32 ----
#pragma unroll
    for (int ks = 0; ks < 2; ++ks) {
      const int ko = (ks << 5) + (q4 << 3);
      short8 a0 = *reinterpret_cast<const short8*>(&Alds[(wr +      l16) * PITCH + ko]);
      short8 a1 = *reinterpret_cast<const short8*>(&Alds[(wr + 16 + l16) * PITCH + ko]);
      short8 b0 = *reinterpret_cast<const short8*>(&Blds[(wc +      l16) * PITCH + ko]);
      short8 b1 = *reinterpret_cast<const short8*>(&Blds[(wc + 16 + l16) * PITCH + ko]);
      acc[0][0] = __builtin_amdgcn_mfma_f32_16x16x32_bf16(a0, b0, acc[0][0], 0, 0, 0);
      acc[0][1] = __builtin_amdgcn_mfma_f32_16x16x32_bf16(a0, b1, acc[0][1], 0, 0, 0);
      acc[1][0] = __builtin_amdgcn_mfma_f32_16x16x32_bf16(a1, b0, acc[1][0], 0, 0, 0);
      acc[1][1] = __builtin_amdgcn_mfma_f32_16x16x32_bf16(a1, b1, acc[1][1], 0, 0, 0);
    }

    // ---- channel boundary: online softmax update, reset accumulators ----
    if (kb == 5) {
#pragma unroll
      for (int fr = 0; fr < 2; ++fr)
#pragma unroll
        for (int fc = 0; fc < 2; ++fc)
#pragma unroll
          for (int r = 0; r < 4; ++r) {
            const int idx = ((fr << 1) + fc) * 4 + r;
            float res = ev[idx] - 2.0f * acc[fr][fc][r];
            float mi = m[idx];
            if (res <= mi) {
              s[idx] += __expf(res - mi);
            } else {
              s[idx] = s[idx] * __expf(mi - res) + 1.0f;
              m[idx] = res;
            }
            acc[fr][fc][r] = 0.0f;
            ev[idx] = 0.0f;
          }
    }

    kb = kn; c = cn;
#pragma unroll
    for (int p = 0; p < 4; ++p) pa[p] = na[p];
#pragma unroll
    for (int p = 0; p < 16; ++p) pb[p] = nb[p];
  }

  // ---- max(softmax) = 1/s ; weight by label; clip; reduce ----
  float local = 0.0f;
  const int* lb = Lab + (size_t)n * plane;
#pragma unroll
  for (int fr = 0; fr < 2; ++fr)
#pragma unroll
    for (int fc = 0; fc < 2; ++fc)
#pragma unroll
      for (int r = 0; r < 4; ++r) {
        const int idx = ((fr << 1) + fc) * 4 + r;
        const int pr = i0 + wr + (fr << 4) + (q4 << 2) + r;
        const int pc = j0 + wc + (fc << 4) + l16;
        float val = 1.0f / s[idx];
        float d = val * (float)lb[pr * Ww + pc];
        d = fminf(fmaxf(d, 1e-12f), 1e12f);
        local += d;
      }
#pragma unroll
  for (int off = 32; off > 0; off >>= 1) local += __shfl_down(local, off, 64);
  if (l == 0) red[w] = local;
  __syncthreads();
  if (t == 0) {
    float bs = (red[0] + red[1] + red[2] + red[3]) * (1.0f / 4718592.0f);
    atomicAdd(Out, bs);
  }
}

extern "C" void kernel_launch(void* const* d_in, const int* in_sizes, int n_in,
                              void* d_out, int out_size, void* d_ws, size_t ws_size,
                              hipStream_t stream) {
  const float* X   = (const float*)d_in[0];
  const float* Cen = (const float*)d_in[1];
  const int*   Lab = (const int*)d_in[2];
  float* Out = (float*)d_out;
  hipMemsetAsync(Out, 0, (size_t)out_size * sizeof(float), stream);
  hipLaunchKernelGGL(center_loss, dim3(Nn * 36), dim3(256), 0, stream,
                     X, Cen, Lab, Out);
}